// Round 3
// baseline (598.515 us; speedup 1.0000x reference)
//
#include <hip/hip_runtime.h>

#define NN 32
#define CC 256
#define LL 1024
#define IC 128
#define R2 9
#define DA 9216
#define DOUT 131072
#define EPSF 1e-5f

typedef __attribute__((ext_vector_type(8))) short short8;
typedef __attribute__((ext_vector_type(4))) float f32x4;

__device__ __forceinline__ ushort bf_rne(float f) {
  union { float f; unsigned u; } v;
  v.f = f;
  unsigned u = v.u;
  u += 0x7FFF + ((u >> 16) & 1);
  return (ushort)(u >> 16);
}

// ---------------- K0: xt[n][l][c] bf16 <- x[n][c][l] fp32 -------------------
// grid (8 l-tiles, 32 n), block 256. Reads coalesced (lanes = consecutive l);
// 8B writes scatter at 512B stride but the block fills complete 512B rows, so
// L2 write-combines before HBM writeback.
__global__ __launch_bounds__(256) void k_xt(const float* __restrict__ x,
                                            ushort* __restrict__ xt) {
  int n = blockIdx.y;
  int l = blockIdx.x * 128 + (threadIdx.x & 127);
  int chalf = (threadIdx.x >> 7) * 128;
  const float* xn = x + ((size_t)n * CC) * LL;
  ushort* xr = xt + ((size_t)n * LL + l) * CC + chalf;
#pragma unroll 4
  for (int c4 = 0; c4 < 32; c4++) {
    float a = xn[(size_t)(chalf + c4 * 4 + 0) * LL + l];
    float b = xn[(size_t)(chalf + c4 * 4 + 1) * LL + l];
    float c = xn[(size_t)(chalf + c4 * 4 + 2) * LL + l];
    float d = xn[(size_t)(chalf + c4 * 4 + 3) * LL + l];
    ushort4 o;
    o.x = bf_rne(a); o.y = bf_rne(b); o.z = bf_rne(c); o.w = bf_rne(d);
    *(ushort4*)(xr + c4 * 4) = o;
  }
}

// ---------------- K1: q = wq*x, k = wk*x via bf16 MFMA ----------------------
// grid (8 = mt*4lt? -> bx&1 = q/k select, bx>>1 = l-tile, by = n), block 256.
// Per wave: M=32 rows of W (a-frags in regs, K=256 fully), L=256 via 16 tiles.
// B-frags straight from global xt (k-contiguous layout), fp32 accum.
__global__ __launch_bounds__(256, 1) void k_qk(const ushort* __restrict__ xt,
                                               const float* __restrict__ wq,
                                               const float* __restrict__ wk,
                                               float* __restrict__ q,
                                               float* __restrict__ k) {
  int bx = blockIdx.x;
  int n = blockIdx.y;
  int mt = bx & 1, lt = bx >> 1;
  int l0 = lt * 256;
  int t = threadIdx.x;
  int lane = t & 63, wv = t >> 6;
  int m16 = lane & 15, kg = lane >> 4;
  const float* wrow = mt ? wk : wq;

  short8 a[2][8];
#pragma unroll
  for (int ms = 0; ms < 2; ms++)
#pragma unroll
    for (int kc = 0; kc < 8; kc++) {
      const float* ap =
          wrow + (size_t)(wv * 32 + ms * 16 + m16) * CC + kc * 32 + kg * 8;
      short8 v;
#pragma unroll
      for (int j = 0; j < 8; j++) v[j] = (short)bf_rne(ap[j]);
      a[ms][kc] = v;
    }

  f32x4 acc0[16], acc1[16];
#pragma unroll
  for (int i = 0; i < 16; i++) {
    acc0[i] = (f32x4){0.f, 0.f, 0.f, 0.f};
    acc1[i] = (f32x4){0.f, 0.f, 0.f, 0.f};
  }

  const ushort* xrow = xt + ((size_t)n * LL + l0 + m16) * CC + kg * 8;
#pragma unroll
  for (int kc = 0; kc < 8; kc++) {
#pragma unroll
    for (int ls = 0; ls < 16; ls++) {
      short8 b = *(const short8*)(xrow + (size_t)ls * 16 * CC + kc * 32);
      acc0[ls] =
          __builtin_amdgcn_mfma_f32_16x16x32_bf16(a[0][kc], b, acc0[ls], 0, 0, 0);
      acc1[ls] =
          __builtin_amdgcn_mfma_f32_16x16x32_bf16(a[1][kc], b, acc1[ls], 0, 0, 0);
    }
  }

  float* outp = (mt ? k : q) + (size_t)n * IC * LL;
  int mq = kg * 4;
#pragma unroll
  for (int ls = 0; ls < 16; ls++) {
    int col = l0 + ls * 16 + m16;
#pragma unroll
    for (int r = 0; r < 4; r++) {
      outp[(size_t)(wv * 32 + mq + r) * LL + col] = acc0[ls][r];
      outp[(size_t)(wv * 32 + 16 + mq + r) * LL + col] = acc1[ls][r];
    }
  }
}

// ---------------- K2: local 3x3 attention scores, f2 += 2*(q.k_patch) -------
__global__ __launch_bounds__(256) void k_attn(const float* __restrict__ q,
                                              const float* __restrict__ k,
                                              float* __restrict__ f2) {
  int n = blockIdx.x;
  int c0 = blockIdx.y * 32;
  int l = blockIdx.z * 256 + threadIdx.x;
  int h = l >> 5, w = l & 31;
  const float* qn = q + (size_t)n * IC * LL;
  const float* kn = k + (size_t)n * IC * LL;
  bool val[9];
  int off[9];
#pragma unroll
  for (int i = 0; i < 3; i++)
#pragma unroll
    for (int j = 0; j < 3; j++) {
      int r = i * 3 + j;
      int hh = h + i - 1, ww = w + j - 1;
      val[r] = (hh >= 0 && hh < 32 && ww >= 0 && ww < 32);
      off[r] = hh * 32 + ww;
    }
  float acc[9];
#pragma unroll
  for (int r = 0; r < 9; r++) acc[r] = 0.f;
#pragma unroll 4
  for (int cc = 0; cc < 32; cc++) {
    int c = c0 + cc;
    float qv = qn[c * LL + l];
    const float* kc = kn + c * LL;
#pragma unroll
    for (int r = 0; r < 9; r++) {
      float kv = val[r] ? kc[off[r]] : 0.f;
      acc[r] += qv * kv;
    }
  }
#pragma unroll
  for (int r = 0; r < 9; r++)
    atomicAdd(&f2[(size_t)n * DA + r * LL + l], 2.f * acc[r]);
}

// ---------------- K3: LayerNorm over 9216, in place -------------------------
__global__ __launch_bounds__(256) void k_ln1(float* __restrict__ f2,
                                             const float* __restrict__ g1,
                                             const float* __restrict__ b1) {
  int n = blockIdx.x, t = threadIdx.x;
  float* row = f2 + (size_t)n * DA;
  float4 v[9];
  float s = 0.f, ss = 0.f;
#pragma unroll
  for (int kk = 0; kk < 9; kk++) {
    v[kk] = ((const float4*)row)[t + kk * 256];
    s += v[kk].x + v[kk].y + v[kk].z + v[kk].w;
    ss += v[kk].x * v[kk].x + v[kk].y * v[kk].y + v[kk].z * v[kk].z +
          v[kk].w * v[kk].w;
  }
#pragma unroll
  for (int o = 32; o; o >>= 1) {
    s += __shfl_down(s, o);
    ss += __shfl_down(ss, o);
  }
  __shared__ float ps[4], pss[4], stats[2];
  int wid = t >> 6, lid = t & 63;
  if (lid == 0) { ps[wid] = s; pss[wid] = ss; }
  __syncthreads();
  if (t == 0) {
    float S = ps[0] + ps[1] + ps[2] + ps[3];
    float SS = pss[0] + pss[1] + pss[2] + pss[3];
    float mu = S / DA;
    float var = SS / DA - mu * mu;
    stats[0] = mu;
    stats[1] = rsqrtf(var + EPSF);
  }
  __syncthreads();
  float mu = stats[0], rs = stats[1];
#pragma unroll
  for (int kk = 0; kk < 9; kk++) {
    float4 g = ((const float4*)g1)[t + kk * 256];
    float4 b = ((const float4*)b1)[t + kk * 256];
    float4 o;
    o.x = (v[kk].x - mu) * rs * g.x + b.x;
    o.y = (v[kk].y - mu) * rs * g.y + b.y;
    o.z = (v[kk].z - mu) * rs * g.z + b.z;
    o.w = (v[kk].w - mu) * rs * g.w + b.w;
    ((float4*)row)[t + kk * 256] = o;
  }
}

// ---------------- K4: h1 = relu(fln @ w1^T + b1), n-split x4 ----------------
// grid (256 o, 4 nsplit), block 256.
__global__ __launch_bounds__(256) void k_ffn1(const float* __restrict__ fln,
                                              const float* __restrict__ w1,
                                              const float* __restrict__ b1,
                                              float* __restrict__ h1) {
  int o = blockIdx.x, nsb = blockIdx.y * 8, t = threadIdx.x;
  float acc[8];
#pragma unroll
  for (int i = 0; i < 8; i++) acc[i] = 0.f;
  const float4* w1r = (const float4*)(w1 + (size_t)o * DA);
  for (int kk = 0; kk < 9; kk++) {
    float4 wv = w1r[t + kk * 256];
#pragma unroll
    for (int i = 0; i < 8; i++) {
      float4 fv = ((const float4*)(fln + (size_t)(nsb + i) * DA))[t + kk * 256];
      acc[i] += wv.x * fv.x + wv.y * fv.y + wv.z * fv.z + wv.w * fv.w;
    }
  }
#pragma unroll
  for (int i = 0; i < 8; i++)
#pragma unroll
    for (int s = 32; s; s >>= 1) acc[i] += __shfl_down(acc[i], s);
  __shared__ float part[4][8];
  int wid = t >> 6, lid = t & 63;
  if (lid == 0) {
#pragma unroll
    for (int i = 0; i < 8; i++) part[wid][i] = acc[i];
  }
  __syncthreads();
  if (t < 8) {
    float sum = part[0][t] + part[1][t] + part[2][t] + part[3][t] + b1[o];
    h1[(size_t)(nsb + t) * CC + o] = fmaxf(sum, 0.f);
  }
}

// ---------------- K5: h2 = h1 @ w2^T + b2, fused LN2 partial stats ----------
// grid 512 (j-tiles of 256), block 256. Stats S[n],SS[n] accumulated via
// shuffle-reduce + atomicAdd (st zeroed by host memset).
__global__ __launch_bounds__(256) void k_ffn2(const float* __restrict__ h1,
                                              const float* __restrict__ w2,
                                              const float* __restrict__ b2,
                                              float* __restrict__ h2,
                                              float* __restrict__ st) {
  __shared__ float h1t[CC * 32];   // [c][n] 32KB
  __shared__ float wt[16 * 256];   // [cc][j] 16KB
  int t = threadIdx.x;
  int j0 = blockIdx.x * 256;
  for (int f = t; f < 32 * CC; f += 256) {
    int n = f & 31, c = f >> 5;
    h1t[c * 32 + n] = h1[n * CC + c];
  }
  int lane = t & 63, wid = t >> 6;
  int nb = wid * 8;
  int jj = lane * 4;
  float4 acc[8];
#pragma unroll
  for (int i = 0; i < 8; i++) acc[i] = make_float4(0.f, 0.f, 0.f, 0.f);

  for (int c0 = 0; c0 < CC; c0 += 16) {
    __syncthreads();
#pragma unroll
    for (int u = 0; u < 4; u++) {
      int f = t + u * 256;
      int jrow = f >> 2;
      int qq = f & 3;
      float4 wv = *(const float4*)(w2 + (size_t)(j0 + jrow) * CC + c0 + qq * 4);
      wt[(qq * 4 + 0) * 256 + jrow] = wv.x;
      wt[(qq * 4 + 1) * 256 + jrow] = wv.y;
      wt[(qq * 4 + 2) * 256 + jrow] = wv.z;
      wt[(qq * 4 + 3) * 256 + jrow] = wv.w;
    }
    __syncthreads();
#pragma unroll
    for (int cc = 0; cc < 16; cc++) {
      int c = c0 + cc;
      float4 ha = *(const float4*)&h1t[c * 32 + nb];
      float4 hb = *(const float4*)&h1t[c * 32 + nb + 4];
      float4 wv = *(const float4*)&wt[cc * 256 + jj];
#define FMA_ROW(hc, idx)                                                      \
  acc[idx].x += (hc) * wv.x; acc[idx].y += (hc) * wv.y;                       \
  acc[idx].z += (hc) * wv.z; acc[idx].w += (hc) * wv.w;
      FMA_ROW(ha.x, 0) FMA_ROW(ha.y, 1) FMA_ROW(ha.z, 2) FMA_ROW(ha.w, 3)
      FMA_ROW(hb.x, 4) FMA_ROW(hb.y, 5) FMA_ROW(hb.z, 6) FMA_ROW(hb.w, 7)
#undef FMA_ROW
    }
  }
  float4 bv = *(const float4*)(b2 + j0 + jj);
  float s[8], ss[8];
#pragma unroll
  for (int i = 0; i < 8; i++) {
    int n = nb + i;
    float4 o;
    o.x = acc[i].x + bv.x; o.y = acc[i].y + bv.y;
    o.z = acc[i].z + bv.z; o.w = acc[i].w + bv.w;
    *(float4*)(h2 + (size_t)n * DOUT + j0 + jj) = o;
    s[i] = o.x + o.y + o.z + o.w;
    ss[i] = o.x * o.x + o.y * o.y + o.z * o.z + o.w * o.w;
  }
#pragma unroll
  for (int off = 32; off; off >>= 1)
#pragma unroll
    for (int i = 0; i < 8; i++) {
      s[i] += __shfl_down(s[i], off);
      ss[i] += __shfl_down(ss[i], off);
    }
  if (lane == 0) {
#pragma unroll
    for (int i = 0; i < 8; i++) {
      atomicAdd(&st[nb + i], s[i]);
      atomicAdd(&st[32 + nb + i], ss[i]);
    }
  }
}

// ---------------- K7: out = BN(y @ w_out^T) + x, y = LN2(h2)*g2+b2 ----------
__global__ __launch_bounds__(256) void k_out(
    const float* __restrict__ h2, const float* __restrict__ st,
    const float* __restrict__ g2, const float* __restrict__ b2,
    const float* __restrict__ w_out, const float* __restrict__ bn_g,
    const float* __restrict__ bn_b, const float* __restrict__ bn_m,
    const float* __restrict__ bn_v, const float* __restrict__ x,
    float* __restrict__ out) {
  __shared__ float wt[IC * 32];    // [o][Os] 16KB
  __shared__ float yt[16 * 256];   // [oc][l] 16KB
  int t = threadIdx.x;
  int l0 = blockIdx.x * 256;
  int Ob = blockIdx.y * 32;
  int n = blockIdx.z;
  for (int f = t; f < IC * 32; f += 256) {
    int Os = f & 31, o = f >> 5;
    wt[o * 32 + Os] = w_out[(size_t)(Ob + Os) * IC + o];
  }
  float mu = st[n] * (1.f / DOUT);
  float rs = rsqrtf(st[32 + n] * (1.f / DOUT) - mu * mu + EPSF);
  int lane = t & 63, wid = t >> 6;
  int Obase = wid * 8;
  int ll = lane * 4;
  float4 acc[8];
#pragma unroll
  for (int i = 0; i < 8; i++) acc[i] = make_float4(0.f, 0.f, 0.f, 0.f);

  for (int o0 = 0; o0 < IC; o0 += 16) {
    __syncthreads();
#pragma unroll
    for (int u = 0; u < 16; u++) {
      int d = (o0 + u) * LL + l0 + t;
      float yv = (h2[(size_t)n * DOUT + d] - mu) * rs * g2[d] + b2[d];
      yt[u * 256 + t] = yv;
    }
    __syncthreads();
#pragma unroll
    for (int oc = 0; oc < 16; oc++) {
      int o = o0 + oc;
      float4 w0 = *(const float4*)&wt[o * 32 + Obase];
      float4 w1v = *(const float4*)&wt[o * 32 + Obase + 4];
      float4 yv = *(const float4*)&yt[oc * 256 + ll];
#define FMA_O(wc, idx)                                                        \
  acc[idx].x += yv.x * (wc); acc[idx].y += yv.y * (wc);                       \
  acc[idx].z += yv.z * (wc); acc[idx].w += yv.w * (wc);
      FMA_O(w0.x, 0) FMA_O(w0.y, 1) FMA_O(w0.z, 2) FMA_O(w0.w, 3)
      FMA_O(w1v.x, 4) FMA_O(w1v.y, 5) FMA_O(w1v.z, 6) FMA_O(w1v.w, 7)
#undef FMA_O
    }
  }
#pragma unroll
  for (int i = 0; i < 8; i++) {
    int O = Ob + Obase + i;
    float sc = bn_g[O] * rsqrtf(bn_v[O] + EPSF);
    float sh = bn_b[O] - bn_m[O] * sc;
    size_t base = ((size_t)(n * CC + O)) * LL + l0 + ll;
    float4 xv = *(const float4*)(x + base);
    float4 r;
    r.x = acc[i].x * sc + sh + xv.x;
    r.y = acc[i].y * sc + sh + xv.y;
    r.z = acc[i].z * sc + sh + xv.z;
    r.w = acc[i].w * sc + sh + xv.w;
    *(float4*)(out + base) = r;
  }
}

extern "C" void kernel_launch(void* const* d_in, const int* in_sizes, int n_in,
                              void* d_out, int out_size, void* d_ws,
                              size_t ws_size, hipStream_t stream) {
  const float* x = (const float*)d_in[0];
  const float* wq = (const float*)d_in[1];
  const float* wk = (const float*)d_in[2];
  const float* gamma1 = (const float*)d_in[3];
  const float* beta1 = (const float*)d_in[4];
  const float* w1 = (const float*)d_in[5];
  const float* b1 = (const float*)d_in[6];
  const float* w2 = (const float*)d_in[7];
  const float* b2 = (const float*)d_in[8];
  const float* gamma2 = (const float*)d_in[9];
  const float* beta2 = (const float*)d_in[10];
  const float* w_out = (const float*)d_in[11];
  const float* bn_g = (const float*)d_in[12];
  const float* bn_b = (const float*)d_in[13];
  const float* bn_m = (const float*)d_in[14];
  const float* bn_v = (const float*)d_in[15];
  float* outp = (float*)d_out;
  float* ws = (float*)d_ws;

  // ws layout (floats): q(4194304) | k(4194304) | xt(4194304 as ushort x2) |
  //                     f(294912) | st(64) | h1(8192); h2 aliases q.
  float* qb = ws;
  float* kb = ws + 4194304;
  ushort* xtb = (ushort*)(ws + 8388608);
  float* fb = ws + 12582912;
  float* stp = ws + 12877824;
  float* h1b = ws + 12877888;
  float* h2b = qb;

  if (ws_size < 12886080ull * sizeof(float)) return;  // fail visibly

  hipMemsetAsync(fb, 0, (294912 + 64) * sizeof(float), stream);  // f + st
  k_xt<<<dim3(8, 32), 256, 0, stream>>>(x, xtb);
  k_qk<<<dim3(8, 32), 256, 0, stream>>>(xtb, wq, wk, qb, kb);
  k_attn<<<dim3(32, 4, 4), 256, 0, stream>>>(qb, kb, fb);
  k_ln1<<<dim3(32), 256, 0, stream>>>(fb, gamma1, beta1);
  k_ffn1<<<dim3(256, 4), 256, 0, stream>>>(fb, w1, b1, h1b);
  k_ffn2<<<dim3(512), 256, 0, stream>>>(h1b, w2, b2, h2b, stp);
  k_out<<<dim3(4, 8, 32), 256, 0, stream>>>(h2b, stp, gamma2, beta2, w_out,
                                            bn_g, bn_b, bn_m, bn_v, x, outp);
}

// Round 4
// 439.930 us; speedup vs baseline: 1.3605x; 1.3605x over previous
//
#include <hip/hip_runtime.h>

#define NN 32
#define CC 256
#define LL 1024
#define IC 128
#define R2 9
#define DA 9216
#define DOUT 131072
#define EPSF 1e-5f

typedef __attribute__((ext_vector_type(8))) short short8;
typedef __attribute__((ext_vector_type(4))) float f32x4;

__device__ __forceinline__ ushort bf_rne(float f) {
  union { float f; unsigned u; } v;
  v.f = f;
  unsigned u = v.u;
  u += 0x7FFF + ((u >> 16) & 1);
  return (ushort)(u >> 16);
}

// ---------------- K0: xt[n][l][c] bf16 <- x[n][c][l] fp32 -------------------
__global__ __launch_bounds__(256) void k_xt(const float* __restrict__ x,
                                            ushort* __restrict__ xt) {
  int n = blockIdx.y;
  int l = blockIdx.x * 128 + (threadIdx.x & 127);
  int chalf = (threadIdx.x >> 7) * 128;
  const float* xn = x + ((size_t)n * CC) * LL;
  ushort* xr = xt + ((size_t)n * LL + l) * CC + chalf;
#pragma unroll 4
  for (int c4 = 0; c4 < 32; c4++) {
    float a = xn[(size_t)(chalf + c4 * 4 + 0) * LL + l];
    float b = xn[(size_t)(chalf + c4 * 4 + 1) * LL + l];
    float c = xn[(size_t)(chalf + c4 * 4 + 2) * LL + l];
    float d = xn[(size_t)(chalf + c4 * 4 + 3) * LL + l];
    ushort4 o;
    o.x = bf_rne(a); o.y = bf_rne(b); o.z = bf_rne(c); o.w = bf_rne(d);
    *(ushort4*)(xr + c4 * 4) = o;
  }
}

// ---------------- K1: q = wq*x, k = wk*x via bf16 MFMA ----------------------
__global__ __launch_bounds__(256, 1) void k_qk(const ushort* __restrict__ xt,
                                               const float* __restrict__ wq,
                                               const float* __restrict__ wk,
                                               float* __restrict__ q,
                                               float* __restrict__ k) {
  int bx = blockIdx.x;
  int n = blockIdx.y;
  int mt = bx & 1, lt = bx >> 1;
  int l0 = lt * 256;
  int t = threadIdx.x;
  int lane = t & 63, wv = t >> 6;
  int m16 = lane & 15, kg = lane >> 4;
  const float* wrow = mt ? wk : wq;

  short8 a[2][8];
#pragma unroll
  for (int ms = 0; ms < 2; ms++)
#pragma unroll
    for (int kc = 0; kc < 8; kc++) {
      const float* ap =
          wrow + (size_t)(wv * 32 + ms * 16 + m16) * CC + kc * 32 + kg * 8;
      short8 v;
#pragma unroll
      for (int j = 0; j < 8; j++) v[j] = (short)bf_rne(ap[j]);
      a[ms][kc] = v;
    }

  f32x4 acc0[16], acc1[16];
#pragma unroll
  for (int i = 0; i < 16; i++) {
    acc0[i] = (f32x4){0.f, 0.f, 0.f, 0.f};
    acc1[i] = (f32x4){0.f, 0.f, 0.f, 0.f};
  }

  const ushort* xrow = xt + ((size_t)n * LL + l0 + m16) * CC + kg * 8;
#pragma unroll
  for (int kc = 0; kc < 8; kc++) {
#pragma unroll
    for (int ls = 0; ls < 16; ls++) {
      short8 b = *(const short8*)(xrow + (size_t)ls * 16 * CC + kc * 32);
      acc0[ls] =
          __builtin_amdgcn_mfma_f32_16x16x32_bf16(a[0][kc], b, acc0[ls], 0, 0, 0);
      acc1[ls] =
          __builtin_amdgcn_mfma_f32_16x16x32_bf16(a[1][kc], b, acc1[ls], 0, 0, 0);
    }
  }

  float* outp = (mt ? k : q) + (size_t)n * IC * LL;
  int mq = kg * 4;
#pragma unroll
  for (int ls = 0; ls < 16; ls++) {
    int col = l0 + ls * 16 + m16;
#pragma unroll
    for (int r = 0; r < 4; r++) {
      outp[(size_t)(wv * 32 + mq + r) * LL + col] = acc0[ls][r];
      outp[(size_t)(wv * 32 + 16 + mq + r) * LL + col] = acc1[ls][r];
    }
  }
}

// ---------------- K2: local 3x3 attention scores, f2 += 2*(q.k_patch) -------
__global__ __launch_bounds__(256) void k_attn(const float* __restrict__ q,
                                              const float* __restrict__ k,
                                              float* __restrict__ f2) {
  int n = blockIdx.x;
  int c0 = blockIdx.y * 32;
  int l = blockIdx.z * 256 + threadIdx.x;
  int h = l >> 5, w = l & 31;
  const float* qn = q + (size_t)n * IC * LL;
  const float* kn = k + (size_t)n * IC * LL;
  bool val[9];
  int off[9];
#pragma unroll
  for (int i = 0; i < 3; i++)
#pragma unroll
    for (int j = 0; j < 3; j++) {
      int r = i * 3 + j;
      int hh = h + i - 1, ww = w + j - 1;
      val[r] = (hh >= 0 && hh < 32 && ww >= 0 && ww < 32);
      off[r] = hh * 32 + ww;
    }
  float acc[9];
#pragma unroll
  for (int r = 0; r < 9; r++) acc[r] = 0.f;
#pragma unroll 4
  for (int cc = 0; cc < 32; cc++) {
    int c = c0 + cc;
    float qv = qn[c * LL + l];
    const float* kc = kn + c * LL;
#pragma unroll
    for (int r = 0; r < 9; r++) {
      float kv = val[r] ? kc[off[r]] : 0.f;
      acc[r] += qv * kv;
    }
  }
#pragma unroll
  for (int r = 0; r < 9; r++)
    atomicAdd(&f2[(size_t)n * DA + r * LL + l], 2.f * acc[r]);
}

// ---------------- K3: LayerNorm over 9216, in place -------------------------
__global__ __launch_bounds__(256) void k_ln1(float* __restrict__ f2,
                                             const float* __restrict__ g1,
                                             const float* __restrict__ b1) {
  int n = blockIdx.x, t = threadIdx.x;
  float* row = f2 + (size_t)n * DA;
  float4 v[9];
  float s = 0.f, ss = 0.f;
#pragma unroll
  for (int kk = 0; kk < 9; kk++) {
    v[kk] = ((const float4*)row)[t + kk * 256];
    s += v[kk].x + v[kk].y + v[kk].z + v[kk].w;
    ss += v[kk].x * v[kk].x + v[kk].y * v[kk].y + v[kk].z * v[kk].z +
          v[kk].w * v[kk].w;
  }
#pragma unroll
  for (int o = 32; o; o >>= 1) {
    s += __shfl_down(s, o);
    ss += __shfl_down(ss, o);
  }
  __shared__ float ps[4], pss[4], stats[2];
  int wid = t >> 6, lid = t & 63;
  if (lid == 0) { ps[wid] = s; pss[wid] = ss; }
  __syncthreads();
  if (t == 0) {
    float S = ps[0] + ps[1] + ps[2] + ps[3];
    float SS = pss[0] + pss[1] + pss[2] + pss[3];
    float mu = S / DA;
    float var = SS / DA - mu * mu;
    stats[0] = mu;
    stats[1] = rsqrtf(var + EPSF);
  }
  __syncthreads();
  float mu = stats[0], rs = stats[1];
#pragma unroll
  for (int kk = 0; kk < 9; kk++) {
    float4 g = ((const float4*)g1)[t + kk * 256];
    float4 b = ((const float4*)b1)[t + kk * 256];
    float4 o;
    o.x = (v[kk].x - mu) * rs * g.x + b.x;
    o.y = (v[kk].y - mu) * rs * g.y + b.y;
    o.z = (v[kk].z - mu) * rs * g.z + b.z;
    o.w = (v[kk].w - mu) * rs * g.w + b.w;
    ((float4*)row)[t + kk * 256] = o;
  }
}

// ---------------- K4: h1 = relu(fln @ w1^T + b1), n-split x4 ----------------
__global__ __launch_bounds__(256) void k_ffn1(const float* __restrict__ fln,
                                              const float* __restrict__ w1,
                                              const float* __restrict__ b1,
                                              float* __restrict__ h1) {
  int o = blockIdx.x, nsb = blockIdx.y * 8, t = threadIdx.x;
  float acc[8];
#pragma unroll
  for (int i = 0; i < 8; i++) acc[i] = 0.f;
  const float4* w1r = (const float4*)(w1 + (size_t)o * DA);
  for (int kk = 0; kk < 9; kk++) {
    float4 wv = w1r[t + kk * 256];
#pragma unroll
    for (int i = 0; i < 8; i++) {
      float4 fv = ((const float4*)(fln + (size_t)(nsb + i) * DA))[t + kk * 256];
      acc[i] += wv.x * fv.x + wv.y * fv.y + wv.z * fv.z + wv.w * fv.w;
    }
  }
#pragma unroll
  for (int i = 0; i < 8; i++)
#pragma unroll
    for (int s = 32; s; s >>= 1) acc[i] += __shfl_down(acc[i], s);
  __shared__ float part[4][8];
  int wid = t >> 6, lid = t & 63;
  if (lid == 0) {
#pragma unroll
    for (int i = 0; i < 8; i++) part[wid][i] = acc[i];
  }
  __syncthreads();
  if (t < 8) {
    float sum = part[0][t] + part[1][t] + part[2][t] + part[3][t] + b1[o];
    h1[(size_t)(nsb + t) * CC + o] = fmaxf(sum, 0.f);
  }
}

// ---------------- K5: h2 = h1 @ w2^T + b2, per-block LN2 partials -----------
// grid 1024 (j-tiles of 128), block 256, LDS 40KB -> 4 blocks/CU.
// Register tile 4n x 4j. Stats written NON-atomically to st_part[bx][64].
__global__ __launch_bounds__(256) void k_ffn2(const float* __restrict__ h1,
                                              const float* __restrict__ w2,
                                              const float* __restrict__ b2,
                                              float* __restrict__ h2,
                                              float* __restrict__ st_part) {
  __shared__ float h1t[CC * 32];   // [c][n] 32KB
  __shared__ float wt[16 * 128];   // [cc][j] 8KB
  int t = threadIdx.x;
  int j0 = blockIdx.x * 128;
  for (int f = t; f < 32 * CC; f += 256) {
    int n = f & 31, c = f >> 5;
    h1t[c * 32 + n] = h1[n * CC + c];
  }
  int lane = t & 63, wid = t >> 6;
  int ng = lane >> 5;
  int n4 = wid * 8 + ng * 4;
  int jj = (lane & 31) * 4;
  float4 acc[4];
#pragma unroll
  for (int i = 0; i < 4; i++) acc[i] = make_float4(0.f, 0.f, 0.f, 0.f);

  for (int c0 = 0; c0 < CC; c0 += 16) {
    __syncthreads();
#pragma unroll
    for (int u = 0; u < 2; u++) {
      int f = t + u * 256;   // 0..511 float4-units
      int jrow = f >> 2;
      int qq = f & 3;
      float4 wv = *(const float4*)(w2 + (size_t)(j0 + jrow) * CC + c0 + qq * 4);
      wt[(qq * 4 + 0) * 128 + jrow] = wv.x;
      wt[(qq * 4 + 1) * 128 + jrow] = wv.y;
      wt[(qq * 4 + 2) * 128 + jrow] = wv.z;
      wt[(qq * 4 + 3) * 128 + jrow] = wv.w;
    }
    __syncthreads();
#pragma unroll
    for (int cc = 0; cc < 16; cc++) {
      float4 ha = *(const float4*)&h1t[(c0 + cc) * 32 + n4];
      float4 wv = *(const float4*)&wt[cc * 128 + jj];
#define FMA_ROW(hc, idx)                                                      \
  acc[idx].x += (hc) * wv.x; acc[idx].y += (hc) * wv.y;                       \
  acc[idx].z += (hc) * wv.z; acc[idx].w += (hc) * wv.w;
      FMA_ROW(ha.x, 0) FMA_ROW(ha.y, 1) FMA_ROW(ha.z, 2) FMA_ROW(ha.w, 3)
#undef FMA_ROW
    }
  }
  float4 bv = *(const float4*)(b2 + j0 + jj);
  float s[4], ss[4];
#pragma unroll
  for (int i = 0; i < 4; i++) {
    int n = n4 + i;
    float4 o;
    o.x = acc[i].x + bv.x; o.y = acc[i].y + bv.y;
    o.z = acc[i].z + bv.z; o.w = acc[i].w + bv.w;
    *(float4*)(h2 + (size_t)n * DOUT + j0 + jj) = o;
    s[i] = o.x + o.y + o.z + o.w;
    ss[i] = o.x * o.x + o.y * o.y + o.z * o.z + o.w * o.w;
  }
#pragma unroll
  for (int off = 16; off; off >>= 1)
#pragma unroll
    for (int i = 0; i < 4; i++) {
      s[i] += __shfl_down(s[i], off, 32);
      ss[i] += __shfl_down(ss[i], off, 32);
    }
  if ((lane & 31) == 0) {
    float* dst = st_part + (size_t)blockIdx.x * 64;
#pragma unroll
    for (int i = 0; i < 4; i++) {
      dst[n4 + i] = s[i];
      dst[32 + n4 + i] = ss[i];
    }
  }
}

// ---------------- K6: reduce st_part[1024][64] -> st[64] --------------------
__global__ __launch_bounds__(256) void k_stat(const float* __restrict__ st_part,
                                              float* __restrict__ st) {
  int e = blockIdx.x;   // 0..63
  int t = threadIdx.x;
  float s = 0.f;
  for (int p = t; p < 1024; p += 256) s += st_part[(size_t)p * 64 + e];
#pragma unroll
  for (int off = 32; off; off >>= 1) s += __shfl_down(s, off);
  __shared__ float ps[4];
  if ((t & 63) == 0) ps[t >> 6] = s;
  __syncthreads();
  if (t == 0) st[e] = ps[0] + ps[1] + ps[2] + ps[3];
}

// ---------------- K7: out = BN(y @ w_out^T) + x, y = LN2(h2)*g2+b2 ----------
__global__ __launch_bounds__(256) void k_out(
    const float* __restrict__ h2, const float* __restrict__ st,
    const float* __restrict__ g2, const float* __restrict__ b2,
    const float* __restrict__ w_out, const float* __restrict__ bn_g,
    const float* __restrict__ bn_b, const float* __restrict__ bn_m,
    const float* __restrict__ bn_v, const float* __restrict__ x,
    float* __restrict__ out) {
  __shared__ float wt[IC * 32];    // [o][Os] 16KB
  __shared__ float yt[16 * 256];   // [oc][l] 16KB
  int t = threadIdx.x;
  int l0 = blockIdx.x * 256;
  int Ob = blockIdx.y * 32;
  int n = blockIdx.z;
  for (int f = t; f < IC * 32; f += 256) {
    int Os = f & 31, o = f >> 5;
    wt[o * 32 + Os] = w_out[(size_t)(Ob + Os) * IC + o];
  }
  float mu = st[n] * (1.f / DOUT);
  float rs = rsqrtf(st[32 + n] * (1.f / DOUT) - mu * mu + EPSF);
  int lane = t & 63, wid = t >> 6;
  int Obase = wid * 8;
  int ll = lane * 4;
  float4 acc[8];
#pragma unroll
  for (int i = 0; i < 8; i++) acc[i] = make_float4(0.f, 0.f, 0.f, 0.f);

  for (int o0 = 0; o0 < IC; o0 += 16) {
    __syncthreads();
#pragma unroll
    for (int u = 0; u < 16; u++) {
      int d = (o0 + u) * LL + l0 + t;
      float yv = (h2[(size_t)n * DOUT + d] - mu) * rs * g2[d] + b2[d];
      yt[u * 256 + t] = yv;
    }
    __syncthreads();
#pragma unroll
    for (int oc = 0; oc < 16; oc++) {
      int o = o0 + oc;
      float4 w0 = *(const float4*)&wt[o * 32 + Obase];
      float4 w1v = *(const float4*)&wt[o * 32 + Obase + 4];
      float4 yv = *(const float4*)&yt[oc * 256 + ll];
#define FMA_O(wc, idx)                                                        \
  acc[idx].x += yv.x * (wc); acc[idx].y += yv.y * (wc);                       \
  acc[idx].z += yv.z * (wc); acc[idx].w += yv.w * (wc);
      FMA_O(w0.x, 0) FMA_O(w0.y, 1) FMA_O(w0.z, 2) FMA_O(w0.w, 3)
      FMA_O(w1v.x, 4) FMA_O(w1v.y, 5) FMA_O(w1v.z, 6) FMA_O(w1v.w, 7)
#undef FMA_O
    }
  }
#pragma unroll
  for (int i = 0; i < 8; i++) {
    int O = Ob + Obase + i;
    float sc = bn_g[O] * rsqrtf(bn_v[O] + EPSF);
    float sh = bn_b[O] - bn_m[O] * sc;
    size_t base = ((size_t)(n * CC + O)) * LL + l0 + ll;
    float4 xv = *(const float4*)(x + base);
    float4 r;
    r.x = acc[i].x * sc + sh + xv.x;
    r.y = acc[i].y * sc + sh + xv.y;
    r.z = acc[i].z * sc + sh + xv.z;
    r.w = acc[i].w * sc + sh + xv.w;
    *(float4*)(out + base) = r;
  }
}

extern "C" void kernel_launch(void* const* d_in, const int* in_sizes, int n_in,
                              void* d_out, int out_size, void* d_ws,
                              size_t ws_size, hipStream_t stream) {
  const float* x = (const float*)d_in[0];
  const float* wq = (const float*)d_in[1];
  const float* wk = (const float*)d_in[2];
  const float* gamma1 = (const float*)d_in[3];
  const float* beta1 = (const float*)d_in[4];
  const float* w1 = (const float*)d_in[5];
  const float* b1 = (const float*)d_in[6];
  const float* w2 = (const float*)d_in[7];
  const float* b2 = (const float*)d_in[8];
  const float* gamma2 = (const float*)d_in[9];
  const float* beta2 = (const float*)d_in[10];
  const float* w_out = (const float*)d_in[11];
  const float* bn_g = (const float*)d_in[12];
  const float* bn_b = (const float*)d_in[13];
  const float* bn_m = (const float*)d_in[14];
  const float* bn_v = (const float*)d_in[15];
  float* outp = (float*)d_out;
  float* ws = (float*)d_ws;

  // ws layout (floats): q(4194304) | k(4194304) | xt(16MB as ushort) |
  //   f(294912) | st(64) | h1(8192) | st_part(65536); h2 aliases q.
  float* qb = ws;
  float* kb = ws + 4194304;
  ushort* xtb = (ushort*)(ws + 8388608);
  float* fb = ws + 12582912;
  float* stp = ws + 12877824;
  float* h1b = ws + 12877888;
  float* spart = ws + 12886080;
  float* h2b = qb;

  if (ws_size < 12951616ull * sizeof(float)) return;  // fail visibly

  hipMemsetAsync(fb, 0, 294912 * sizeof(float), stream);  // f (attn atomics)
  k_xt<<<dim3(8, 32), 256, 0, stream>>>(x, xtb);
  k_qk<<<dim3(8, 32), 256, 0, stream>>>(xtb, wq, wk, qb, kb);
  k_attn<<<dim3(32, 4, 4), 256, 0, stream>>>(qb, kb, fb);
  k_ln1<<<dim3(32), 256, 0, stream>>>(fb, gamma1, beta1);
  k_ffn1<<<dim3(256, 4), 256, 0, stream>>>(fb, w1, b1, h1b);
  k_ffn2<<<dim3(1024), 256, 0, stream>>>(h1b, w2, b2, h2b, spart);
  k_stat<<<dim3(64), 256, 0, stream>>>(spart, stp);
  k_out<<<dim3(4, 8, 32), 256, 0, stream>>>(h2b, stp, gamma2, beta2, w_out,
                                            bn_g, bn_b, bn_m, bn_v, x, outp);
}